// Round 5
// baseline (131.620 us; speedup 1.0000x reference)
//
#include <hip/hip_runtime.h>

#define NB 32
#define NN 256
#define DD 64
#define SROW 68          // LDS row stride in floats (17 float4); measured 0 bank conflicts
#define FMAXV 3.402823466e+38f

// R11: single dispatch, one block per batch (32 x 1024), all reductions
// intra-block (R10 skeleton). R10's conv loops were rolled by the compiler
// (VGPR_Count=32) -> per-step addressing + serialized lgkmcnt waits; weights
// re-s_loaded 4x (cc-outer). This version: fully-unrolled k4-outer /
// cc-inner conv body -- per k4: 4 ds_read_b128 (h) + 8 uniform float4
// weight loads (s_load, once per k) + 128 FMA, all compile-time indices.
// Accumulators ti[4][4]+tj[4][4] = 32 VGPR live; cap 128 via
// __launch_bounds__(1024,4). Window model: ~82us fixed (40 fill + ~42
// launch); kernel target ~20us -> ~100-108us total.

__device__ __forceinline__ void conv_matvec(
    const float* Hs, int l, int d0, const float* __restrict__ We,
    float ti[4][4], float tj[4][4])
{
#pragma unroll
    for (int cc = 0; cc < 4; ++cc)
#pragma unroll
        for (int j = 0; j < 4; ++j) { ti[cc][j] = 0.f; tj[cc][j] = 0.f; }

    const float* hr0 = Hs + (size_t)(0 * 64 + l) * SROW;
    const float* hr1 = Hs + (size_t)(1 * 64 + l) * SROW;
    const float* hr2 = Hs + (size_t)(2 * 64 + l) * SROW;
    const float* hr3 = Hs + (size_t)(3 * 64 + l) * SROW;

#pragma unroll
    for (int k4 = 0; k4 < 16; ++k4) {
        float4 h0 = *(const float4*)(hr0 + k4 * 4);
        float4 h1 = *(const float4*)(hr1 + k4 * 4);
        float4 h2 = *(const float4*)(hr2 + k4 * 4);
        float4 h3 = *(const float4*)(hr3 + k4 * 4);
        const float ha[4][4] = {{h0.x, h0.y, h0.z, h0.w},
                                {h1.x, h1.y, h1.z, h1.w},
                                {h2.x, h2.y, h2.z, h2.w},
                                {h3.x, h3.y, h3.z, h3.w}};
#pragma unroll
        for (int kk = 0; kk < 4; ++kk) {
            const int k = k4 * 4 + kk;
            float4 wi = *(const float4*)(We + k * DD + d0);          // uniform -> s_load
            float4 wj = *(const float4*)(We + (DD + k) * DD + d0);   // uniform -> s_load
            const float wiv[4] = {wi.x, wi.y, wi.z, wi.w};
            const float wjv[4] = {wj.x, wj.y, wj.z, wj.w};
#pragma unroll
            for (int cc = 0; cc < 4; ++cc) {
#pragma unroll
                for (int j = 0; j < 4; ++j) {
                    ti[cc][j] = fmaf(ha[cc][kk], wiv[j], ti[cc][j]);
                    tj[cc][j] = fmaf(ha[cc][kk], wjv[j], tj[cc][j]);
                }
            }
        }
    }
}

__device__ __forceinline__ void reduce_minmax(const float tj[4][4],
                                              float rmax[4], float rmin[4])
{
    float mx[4], mn[4];
#pragma unroll
    for (int j = 0; j < 4; ++j) {
        mx[j] = fmaxf(fmaxf(tj[0][j], tj[1][j]), fmaxf(tj[2][j], tj[3][j]));
        mn[j] = fminf(fminf(tj[0][j], tj[1][j]), fminf(tj[2][j], tj[3][j]));
    }
#pragma unroll
    for (int m = 1; m < 64; m <<= 1) {
#pragma unroll
        for (int j = 0; j < 4; ++j) {
            mx[j] = fmaxf(mx[j], __shfl_xor(mx[j], m, 64));
            mn[j] = fminf(mn[j], __shfl_xor(mn[j], m, 64));
        }
    }
#pragma unroll
    for (int j = 0; j < 4; ++j) { rmax[j] = mx[j]; rmin[j] = mn[j]; }
}

__global__ __launch_bounds__(1024, 4) void k_all(
    const float* __restrict__ x,
    const float* __restrict__ W1,  const float* __restrict__ b1,
    const float* __restrict__ g1,  const float* __restrict__ beta1,
    const float* __restrict__ We1, const float* __restrict__ be1,
    const float* __restrict__ ge1, const float* __restrict__ bte1,
    const float* __restrict__ We2, const float* __restrict__ be2,
    const float* __restrict__ ge2, const float* __restrict__ bte2,
    const float* __restrict__ Wg1, const float* __restrict__ bg1,
    const float* __restrict__ Wg2, const float* __restrict__ bg2,
    float* __restrict__ out)
{
    __shared__ __align__(16) float Hs[NN * SROW];   // 69,632 B
    __shared__ float xg[2 * DD];
    __shared__ float hid[DD];

    const int b  = blockIdx.x;
    const int l  = threadIdx.x & 63;                                 // node lane
    const int w  = __builtin_amdgcn_readfirstlane(threadIdx.x >> 6); // wave 0..15 (SGPR)
    const int d0 = w * 4;                                            // wave's 4-dim slice

    // ================= layer 1: h1 -> Hs =================
#pragma unroll
    for (int cc = 0; cc < 4; ++cc) {
        const int n = cc * 64 + l;
        float4 xv = *(const float4*)(x + ((size_t)b * NN + n) * 4);
        float a[4];
#pragma unroll
        for (int j = 0; j < 4; ++j) a[j] = b1[d0 + j];
#pragma unroll
        for (int j = 0; j < 4; ++j) a[j] = fmaf(xv.x, W1[0 * DD + d0 + j], a[j]);
#pragma unroll
        for (int j = 0; j < 4; ++j) a[j] = fmaf(xv.y, W1[1 * DD + d0 + j], a[j]);
#pragma unroll
        for (int j = 0; j < 4; ++j) a[j] = fmaf(xv.z, W1[2 * DD + d0 + j], a[j]);
#pragma unroll
        for (int j = 0; j < 4; ++j) a[j] = fmaf(xv.w, W1[3 * DD + d0 + j], a[j]);
        float h[4];
#pragma unroll
        for (int j = 0; j < 4; ++j) h[j] = g1[d0 + j] * fmaxf(a[j], 0.f) + beta1[d0 + j];
        *(float4*)(Hs + (size_t)n * SROW + d0) = make_float4(h[0], h[1], h[2], h[3]);
    }
    __syncthreads();

    float ti[4][4], tj[4][4];
    float rmax[4], rmin[4];

    // ============ conv1: matvec + in-register tj reduce ============
    conv_matvec(Hs, l, d0, We1, ti, tj);
    reduce_minmax(tj, rmax, rmin);
    __syncthreads();   // all conv1 Hs reads complete before epilogue overwrites

    // ============ conv1 epilogue -> Hs (monotone bn o max) ============
#pragma unroll
    for (int cc = 0; cc < 4; ++cc) {
        const int n = cc * 64 + l;
        float h[4];
#pragma unroll
        for (int j = 0; j < 4; ++j) {
            float gv = ge1[d0 + j];
            float sv = ti[cc][j] + (gv >= 0.f ? rmax[j] : rmin[j]) + be1[d0 + j];
            h[j] = gv * fmaxf(sv, 0.f) + bte1[d0 + j];
        }
        *(float4*)(Hs + (size_t)n * SROW + d0) = make_float4(h[0], h[1], h[2], h[3]);
    }
    __syncthreads();

    // ============ conv2: matvec + in-register tj reduce ============
    conv_matvec(Hs, l, d0, We2, ti, tj);
    reduce_minmax(tj, rmax, rmin);
    // no barrier: below touches only registers + xg

    // ============ conv2 epilogue + pooling (in-register) ============
    {
        float sm[4]  = {0.f, 0.f, 0.f, 0.f};
        float mxp[4] = {-FMAXV, -FMAXV, -FMAXV, -FMAXV};
#pragma unroll
        for (int cc = 0; cc < 4; ++cc) {
#pragma unroll
            for (int j = 0; j < 4; ++j) {
                float gv = ge2[d0 + j];
                float sv = ti[cc][j] + (gv >= 0.f ? rmax[j] : rmin[j]) + be2[d0 + j];
                float hv = gv * fmaxf(sv, 0.f) + bte2[d0 + j];
                sm[j]  += hv;
                mxp[j]  = fmaxf(mxp[j], hv);
            }
        }
#pragma unroll
        for (int m = 1; m < 64; m <<= 1) {
#pragma unroll
            for (int j = 0; j < 4; ++j) {
                sm[j]  += __shfl_xor(sm[j], m, 64);
                mxp[j]  = fmaxf(mxp[j], __shfl_xor(mxp[j], m, 64));
            }
        }
        float ssm = sm[0], smxp = mxp[0];
#pragma unroll
        for (int j = 1; j < 4; ++j) {
            ssm  = (l == j) ? sm[j]  : ssm;
            smxp = (l == j) ? mxp[j] : smxp;
        }
        if (l < 4) {
            xg[d0 + l]      = ssm * (1.f / 256.f);
            xg[DD + d0 + l] = smxp;
        }
    }
    __syncthreads();

    // ============ head MLP ============
    const int t = threadIdx.x;
    if (t < DD) {
        float a = bg1[t];
#pragma unroll
        for (int k = 0; k < 2 * DD; ++k) a = fmaf(xg[k], Wg1[k * DD + t], a);
        hid[t] = fmaxf(a, 0.f);
    }
    __syncthreads();
    if (t < 2) {
        float o = bg2[t];
#pragma unroll
        for (int j = 0; j < DD; ++j) o = fmaf(hid[j], Wg2[j * 2 + t], o);
        out[b * 2 + t] = o;
    }
}

extern "C" void kernel_launch(void* const* d_in, const int* in_sizes, int n_in,
                              void* d_out, int out_size, void* d_ws, size_t ws_size,
                              hipStream_t stream) {
    const float* x     = (const float*)d_in[0];
    const float* W1    = (const float*)d_in[1];
    const float* b1    = (const float*)d_in[2];
    const float* g1    = (const float*)d_in[3];
    const float* beta1 = (const float*)d_in[4];
    const float* We1   = (const float*)d_in[5];
    const float* be1   = (const float*)d_in[6];
    const float* ge1   = (const float*)d_in[7];
    const float* bte1  = (const float*)d_in[8];
    const float* We2   = (const float*)d_in[9];
    const float* be2   = (const float*)d_in[10];
    const float* ge2   = (const float*)d_in[11];
    const float* bte2  = (const float*)d_in[12];
    const float* Wg1   = (const float*)d_in[13];
    const float* bg1   = (const float*)d_in[14];
    const float* Wg2   = (const float*)d_in[15];
    const float* bg2   = (const float*)d_in[16];

    k_all<<<dim3(NB), dim3(1024), 0, stream>>>(
        x, W1, b1, g1, beta1,
        We1, be1, ge1, bte1,
        We2, be2, ge2, bte2,
        Wg1, bg1, Wg2, bg2, (float*)d_out);
}

// Round 6
// 122.123 us; speedup vs baseline: 1.0778x; 1.0778x over previous
//
#include <hip/hip_runtime.h>

#define NB 32
#define NN 256
#define DD 64
#define SROW 68          // LDS row stride in floats (17 float4); measured 0 conflicts
#define FMAXV 3.402823466e+38f

// R12: 3-dispatch full-chip pipeline.
// Window model (calibrated R8-R11): dur = 40us fill + ~43us fixed graph/launch
// + sum(kernels) + ~2-5us per extra dispatch. The ~43us is dispatch-count-
// INsensitive, so R10/R11's single-dispatch design just squeezed all FMA work
// onto 32 CUs (48us kernel). Here:
//  - k1/k2: grid 256 (32 batches x 4 node-groups x 2 dim-halves) = 256 CUs.
//  - inner k-loops are PURE s_load+FMA: h row hoisted to 64 VGPRs first
//    (k1 computes layer-1 redundantly per thread -> no LDS, no barrier;
//    k2 does one LDS stage + one b128 hoist). No ds_read/s_load lgkmcnt
//    mixing inside the loop -> no per-iteration full drains (R11's stall).
//  - k3 (32 blocks): conv2 epilogue (per-dim, needs no full row) + pooling
//    + head MLP fused.
// ws layout (floats): TI1 @0 (524288) | TI2 @524288 | PMAX1 @1048576 (8192)
//   | PMIN1 @1056768 | PMAX2 @1064960 | PMIN2 @1073152

__global__ __launch_bounds__(512, 2) void k1_conv(
    const float* __restrict__ x,
    const float* __restrict__ W1,  const float* __restrict__ b1,
    const float* __restrict__ g1,  const float* __restrict__ beta1,
    const float* __restrict__ We1,
    float* __restrict__ TI, float* __restrict__ PMAX, float* __restrict__ PMIN)
{
    const int blk = blockIdx.x;
    const int b   = blk >> 3;
    const int g   = (blk >> 1) & 3;
    const int dh  = blk & 1;
    const int l   = threadIdx.x & 63;                                 // node lane
    const int w   = __builtin_amdgcn_readfirstlane(threadIdx.x >> 6); // wave 0..7
    const int n   = g * 64 + l;
    const int d0  = dh * 32 + w * 4;                                  // wave-uniform

    // full layer-1 row for node n, in registers (redundant across the 16
    // threads covering this node's dim-slices; barrier-free, LDS-free)
    float h[DD];
    {
        float4 xv = *(const float4*)(x + ((size_t)b * NN + n) * 4);
#pragma unroll
        for (int j = 0; j < DD; ++j) {
            float a = b1[j];
            a = fmaf(xv.x, W1[0 * DD + j], a);
            a = fmaf(xv.y, W1[1 * DD + j], a);
            a = fmaf(xv.z, W1[2 * DD + j], a);
            a = fmaf(xv.w, W1[3 * DD + j], a);
            h[j] = g1[j] * fmaxf(a, 0.f) + beta1[j];
        }
    }

    // conv1 matvec: pure s_load(weights)+FMA, h in regs
    float ti[4] = {0.f, 0.f, 0.f, 0.f}, tj[4] = {0.f, 0.f, 0.f, 0.f};
#pragma unroll
    for (int k = 0; k < DD; ++k) {
        const float* wi = We1 + k * DD + d0;          // wave-uniform -> s_load
        const float* wj = We1 + (DD + k) * DD + d0;   // wave-uniform -> s_load
#pragma unroll
        for (int j = 0; j < 4; ++j) {
            ti[j] = fmaf(h[k], wi[j], ti[j]);
            tj[j] = fmaf(h[k], wj[j], tj[j]);
        }
    }
    *(float4*)(TI + ((size_t)(b * NN + n)) * DD + d0) =
        make_float4(ti[0], ti[1], ti[2], ti[3]);

    // tj max/min over this block's 64 nodes
    float mx[4], mn[4];
#pragma unroll
    for (int j = 0; j < 4; ++j) { mx[j] = tj[j]; mn[j] = tj[j]; }
#pragma unroll
    for (int m = 1; m < 64; m <<= 1) {
#pragma unroll
        for (int j = 0; j < 4; ++j) {
            mx[j] = fmaxf(mx[j], __shfl_xor(mx[j], m, 64));
            mn[j] = fminf(mn[j], __shfl_xor(mn[j], m, 64));
        }
    }
    float smx = mx[0], smn = mn[0];
#pragma unroll
    for (int j = 1; j < 4; ++j) {
        smx = (l == j) ? mx[j] : smx;
        smn = (l == j) ? mn[j] : smn;
    }
    if (l < 4) {
        PMAX[(b * 4 + g) * DD + d0 + l] = smx;
        PMIN[(b * 4 + g) * DD + d0 + l] = smn;
    }
}

__global__ __launch_bounds__(512, 2) void k2_conv(
    const float* __restrict__ PMAXin, const float* __restrict__ PMINin,
    const float* __restrict__ be1P, const float* __restrict__ ge1P,
    const float* __restrict__ bte1P,
    const float* __restrict__ We2,
    const float* __restrict__ TIin,
    float* __restrict__ TI2, float* __restrict__ PMAX, float* __restrict__ PMIN)
{
    __shared__ __align__(16) float Hs[64 * SROW];   // 17.4 KB
    const int blk = blockIdx.x;
    const int b   = blk >> 3;
    const int g   = (blk >> 1) & 3;
    const int dh  = blk & 1;
    const int l   = threadIdx.x & 63;
    const int w   = __builtin_amdgcn_readfirstlane(threadIdx.x >> 6);
    const int n   = g * 64 + l;
    const int d0  = dh * 32 + w * 4;   // this wave's conv2 output dims
    const int s0  = w * 8;             // this wave's h2 staging dims

    // stage h2[n, s0..s0+7] (conv1 epilogue) into LDS
    {
        float rmax[8], rmin[8];
#pragma unroll
        for (int j = 0; j < 8; ++j) {
            const int base = b * 4 * DD + s0 + j;
            rmax[j] = fmaxf(fmaxf(PMAXin[base],          PMAXin[base + DD]),
                            fmaxf(PMAXin[base + 2 * DD], PMAXin[base + 3 * DD]));
            rmin[j] = fminf(fminf(PMINin[base],          PMINin[base + DD]),
                            fminf(PMINin[base + 2 * DD], PMINin[base + 3 * DD]));
        }
        const float* tip = TIin + ((size_t)(b * NN + n)) * DD + s0;
        float4 t0 = *(const float4*)tip;
        float4 t1 = *(const float4*)(tip + 4);
        float tiv[8] = {t0.x, t0.y, t0.z, t0.w, t1.x, t1.y, t1.z, t1.w};
        float hh[8];
#pragma unroll
        for (int j = 0; j < 8; ++j) {
            float gv = ge1P[s0 + j];
            float sv = tiv[j] + (gv >= 0.f ? rmax[j] : rmin[j]) + be1P[s0 + j];
            hh[j] = gv * fmaxf(sv, 0.f) + bte1P[s0 + j];
        }
        *(float4*)(Hs + l * SROW + s0)     = make_float4(hh[0], hh[1], hh[2], hh[3]);
        *(float4*)(Hs + l * SROW + s0 + 4) = make_float4(hh[4], hh[5], hh[6], hh[7]);
    }
    __syncthreads();

    // hoist full h2 row to registers (one DS burst, then loop is DS-free)
    float h[DD];
#pragma unroll
    for (int q = 0; q < 16; ++q) {
        float4 hv = *(const float4*)(Hs + l * SROW + q * 4);
        h[q * 4 + 0] = hv.x; h[q * 4 + 1] = hv.y;
        h[q * 4 + 2] = hv.z; h[q * 4 + 3] = hv.w;
    }

    float ti[4] = {0.f, 0.f, 0.f, 0.f}, tj[4] = {0.f, 0.f, 0.f, 0.f};
#pragma unroll
    for (int k = 0; k < DD; ++k) {
        const float* wi = We2 + k * DD + d0;
        const float* wj = We2 + (DD + k) * DD + d0;
#pragma unroll
        for (int j = 0; j < 4; ++j) {
            ti[j] = fmaf(h[k], wi[j], ti[j]);
            tj[j] = fmaf(h[k], wj[j], tj[j]);
        }
    }
    *(float4*)(TI2 + ((size_t)(b * NN + n)) * DD + d0) =
        make_float4(ti[0], ti[1], ti[2], ti[3]);

    float mx[4], mn[4];
#pragma unroll
    for (int j = 0; j < 4; ++j) { mx[j] = tj[j]; mn[j] = tj[j]; }
#pragma unroll
    for (int m = 1; m < 64; m <<= 1) {
#pragma unroll
        for (int j = 0; j < 4; ++j) {
            mx[j] = fmaxf(mx[j], __shfl_xor(mx[j], m, 64));
            mn[j] = fminf(mn[j], __shfl_xor(mn[j], m, 64));
        }
    }
    float smx = mx[0], smn = mn[0];
#pragma unroll
    for (int j = 1; j < 4; ++j) {
        smx = (l == j) ? mx[j] : smx;
        smn = (l == j) ? mn[j] : smn;
    }
    if (l < 4) {
        PMAX[(b * 4 + g) * DD + d0 + l] = smx;
        PMIN[(b * 4 + g) * DD + d0 + l] = smn;
    }
}

// conv2 epilogue (per-dim) + pooling + head MLP, one block per batch
__global__ __launch_bounds__(512) void k3_tail(
    const float* __restrict__ PMAXin, const float* __restrict__ PMINin,
    const float* __restrict__ be2P, const float* __restrict__ ge2P,
    const float* __restrict__ bte2P,
    const float* __restrict__ TI2,
    const float* __restrict__ Wg1, const float* __restrict__ bg1,
    const float* __restrict__ Wg2, const float* __restrict__ bg2,
    float* __restrict__ out)
{
    __shared__ float xg[2 * DD];
    __shared__ float hid[DD];
    const int b  = blockIdx.x;
    const int l  = threadIdx.x & 63;
    const int w  = __builtin_amdgcn_readfirstlane(threadIdx.x >> 6); // 0..7
    const int d0 = w * 8;

    float rmax[8], rmin[8];
#pragma unroll
    for (int j = 0; j < 8; ++j) {
        const int base = b * 4 * DD + d0 + j;
        rmax[j] = fmaxf(fmaxf(PMAXin[base],          PMAXin[base + DD]),
                        fmaxf(PMAXin[base + 2 * DD], PMAXin[base + 3 * DD]));
        rmin[j] = fminf(fminf(PMINin[base],          PMINin[base + DD]),
                        fminf(PMINin[base + 2 * DD], PMINin[base + 3 * DD]));
    }
    float sm[8]  = {0.f, 0.f, 0.f, 0.f, 0.f, 0.f, 0.f, 0.f};
    float mxp[8] = {-FMAXV, -FMAXV, -FMAXV, -FMAXV, -FMAXV, -FMAXV, -FMAXV, -FMAXV};
#pragma unroll
    for (int cc = 0; cc < 4; ++cc) {
        const float* tip = TI2 + ((size_t)(b * NN + cc * 64 + l)) * DD + d0;
        float4 t0 = *(const float4*)tip;
        float4 t1 = *(const float4*)(tip + 4);
        float tiv[8] = {t0.x, t0.y, t0.z, t0.w, t1.x, t1.y, t1.z, t1.w};
#pragma unroll
        for (int j = 0; j < 8; ++j) {
            float gv = ge2P[d0 + j];
            float sv = tiv[j] + (gv >= 0.f ? rmax[j] : rmin[j]) + be2P[d0 + j];
            float hv = gv * fmaxf(sv, 0.f) + bte2P[d0 + j];
            sm[j]  += hv;
            mxp[j]  = fmaxf(mxp[j], hv);
        }
    }
#pragma unroll
    for (int m = 1; m < 64; m <<= 1) {
#pragma unroll
        for (int j = 0; j < 8; ++j) {
            sm[j]  += __shfl_xor(sm[j], m, 64);
            mxp[j]  = fmaxf(mxp[j], __shfl_xor(mxp[j], m, 64));
        }
    }
    float ssm = sm[0], smxp = mxp[0];
#pragma unroll
    for (int j = 1; j < 8; ++j) {
        ssm  = (l == j) ? sm[j]  : ssm;
        smxp = (l == j) ? mxp[j] : smxp;
    }
    if (l < 8) {
        xg[d0 + l]      = ssm * (1.f / 256.f);
        xg[DD + d0 + l] = smxp;
    }
    __syncthreads();

    const int t = threadIdx.x;
    if (t < DD) {
        float a = bg1[t];
#pragma unroll
        for (int k = 0; k < 2 * DD; ++k) a = fmaf(xg[k], Wg1[k * DD + t], a);
        hid[t] = fmaxf(a, 0.f);
    }
    __syncthreads();
    if (t < 2) {
        float o = bg2[t];
#pragma unroll
        for (int j = 0; j < DD; ++j) o = fmaf(hid[j], Wg2[j * 2 + t], o);
        out[b * 2 + t] = o;
    }
}

extern "C" void kernel_launch(void* const* d_in, const int* in_sizes, int n_in,
                              void* d_out, int out_size, void* d_ws, size_t ws_size,
                              hipStream_t stream) {
    const float* x     = (const float*)d_in[0];
    const float* W1    = (const float*)d_in[1];
    const float* b1    = (const float*)d_in[2];
    const float* g1    = (const float*)d_in[3];
    const float* beta1 = (const float*)d_in[4];
    const float* We1   = (const float*)d_in[5];
    const float* be1   = (const float*)d_in[6];
    const float* ge1   = (const float*)d_in[7];
    const float* bte1  = (const float*)d_in[8];
    const float* We2   = (const float*)d_in[9];
    const float* be2   = (const float*)d_in[10];
    const float* ge2   = (const float*)d_in[11];
    const float* bte2  = (const float*)d_in[12];
    const float* Wg1   = (const float*)d_in[13];
    const float* bg1   = (const float*)d_in[14];
    const float* Wg2   = (const float*)d_in[15];
    const float* bg2   = (const float*)d_in[16];

    float* ws    = (float*)d_ws;
    float* TI1   = ws;
    float* TI2   = ws + 524288;
    float* PMAX1 = ws + 1048576;
    float* PMIN1 = ws + 1056768;
    float* PMAX2 = ws + 1064960;
    float* PMIN2 = ws + 1073152;

    k1_conv<<<dim3(NB * 8), dim3(512), 0, stream>>>(
        x, W1, b1, g1, beta1, We1, TI1, PMAX1, PMIN1);
    k2_conv<<<dim3(NB * 8), dim3(512), 0, stream>>>(
        PMAX1, PMIN1, be1, ge1, bte1, We2, TI1, TI2, PMAX2, PMIN2);
    k3_tail<<<dim3(NB), dim3(512), 0, stream>>>(
        PMAX2, PMIN2, be2, ge2, bte2, TI2, Wg1, bg1, Wg2, bg2, (float*)d_out);
}

// Round 7
// 117.551 us; speedup vs baseline: 1.1197x; 1.0389x over previous
//
#include <hip/hip_runtime.h>

#define NB 32
#define NN 256
#define DD 64
#define SROW 68          // LDS row stride (floats); measured 0 bank conflicts w/ b128
#define TPAD 17          // transpose scratch row stride; 2-way max aliasing (free)
#define FMAXV 3.402823466e+38f

// R13: single dispatch (window = ~82us fixed + kernel; R10 proved it at
// 130.8 = 82 + 48.7). Attack the 48.7us kernel:
//  - 1 node x 16 dims per thread (wave = 64 nodes x uniform dim-slice):
//    row hoists drop 128->32 b128/thread; wave's dims uniform -> reduction
//    results live in all lanes, no re-broadcast.
//  - reductions via per-wave LDS TRANSPOSE (write tj[16] rows, read columns,
//    fold 16 in-lane, 4 shuffles) instead of 6-step butterflies: ~36 DS ops
//    vs 192. R10 spent ~16us of serial LDS-pipe on shuffles+reads.
//  - conv inner loop = pure s_load(weights)+FMA over register-staged h
//    chunks (16 floats / chunk, one b128 burst); no ds/s_load mixing inside
//    the FMA run; all register indices static (no scratch).
// Transpose scratch reuses Hs (wave w -> Hs + w*1088, 64x17).

__device__ __forceinline__ void conv_full(
    const float* Hs, int n, int d0, const float* __restrict__ We,
    float ti[16], float tj[16])
{
#pragma unroll
    for (int j = 0; j < 16; ++j) { ti[j] = 0.f; tj[j] = 0.f; }
    const float* hrow = Hs + (size_t)n * SROW;
#pragma unroll 1
    for (int kc = 0; kc < 4; ++kc) {           // rolled: keeps code I$-sized
        float h[16];
#pragma unroll
        for (int q = 0; q < 4; ++q) {
            float4 hv = *(const float4*)(hrow + kc * 16 + 4 * q);
            h[4*q+0] = hv.x; h[4*q+1] = hv.y; h[4*q+2] = hv.z; h[4*q+3] = hv.w;
        }
#pragma unroll
        for (int kk = 0; kk < 16; ++kk) {      // full unroll: static h[] index
            const float hk = h[kk];
            const float* wi = We + (size_t)(kc * 16 + kk) * DD + d0;        // uniform
            const float* wj = We + (size_t)(DD + kc * 16 + kk) * DD + d0;   // uniform
#pragma unroll
            for (int q = 0; q < 4; ++q) {
                float4 a = *(const float4*)(wi + 4 * q);
                float4 c = *(const float4*)(wj + 4 * q);
                ti[4*q+0] = fmaf(hk, a.x, ti[4*q+0]);
                ti[4*q+1] = fmaf(hk, a.y, ti[4*q+1]);
                ti[4*q+2] = fmaf(hk, a.z, ti[4*q+2]);
                ti[4*q+3] = fmaf(hk, a.w, ti[4*q+3]);
                tj[4*q+0] = fmaf(hk, c.x, tj[4*q+0]);
                tj[4*q+1] = fmaf(hk, c.y, tj[4*q+1]);
                tj[4*q+2] = fmaf(hk, c.z, tj[4*q+2]);
                tj[4*q+3] = fmaf(hk, c.w, tj[4*q+3]);
            }
        }
    }
}

__global__ __launch_bounds__(1024, 4) void k_all(
    const float* __restrict__ x,
    const float* __restrict__ W1,  const float* __restrict__ b1,
    const float* __restrict__ g1,  const float* __restrict__ beta1,
    const float* __restrict__ We1, const float* __restrict__ be1,
    const float* __restrict__ ge1, const float* __restrict__ bte1,
    const float* __restrict__ We2, const float* __restrict__ be2,
    const float* __restrict__ ge2, const float* __restrict__ bte2,
    const float* __restrict__ Wg1, const float* __restrict__ bg1,
    const float* __restrict__ Wg2, const float* __restrict__ bg2,
    float* __restrict__ out)
{
    __shared__ __align__(16) float Hs[NN * SROW];   // 69,632 B; also transpose scratch
    __shared__ __align__(16) float PTmax[4][DD], PTmin[4][DD];
    __shared__ __align__(16) float RM[DD], RMn[DD];
    __shared__ __align__(16) float PS[4][DD], PM[4][DD];
    __shared__ __align__(16) float xg[2 * DD];
    __shared__ __align__(16) float hid[DD];

    const int b   = blockIdx.x;
    const int l   = threadIdx.x & 63;                                 // node lane
    const int w   = __builtin_amdgcn_readfirstlane(threadIdx.x >> 6); // wave 0..15
    const int ng  = w >> 2;           // node-group 0..3
    const int d0  = (w & 3) * 16;     // wave-uniform dim slice
    const int n   = ng * 64 + l;      // this thread's node
    const int jd  = l >> 2;           // transpose-read: my dim index (0..15)
    const int cq  = l & 3;            // transpose-read: my node-chunk (0..3)
    float* Ts     = Hs + w * (64 * TPAD);   // per-wave 64x17 scratch

    // ================= P0: layer 1 -> Hs rows =================
    {
        float4 xv = *(const float4*)(x + ((size_t)b * NN + n) * 4);
#pragma unroll
        for (int q = 0; q < 4; ++q) {
            float hq[4];
#pragma unroll
            for (int u = 0; u < 4; ++u) {
                const int d = d0 + 4 * q + u;
                float a = b1[d];
                a = fmaf(xv.x, W1[0 * DD + d], a);
                a = fmaf(xv.y, W1[1 * DD + d], a);
                a = fmaf(xv.z, W1[2 * DD + d], a);
                a = fmaf(xv.w, W1[3 * DD + d], a);
                hq[u] = g1[d] * fmaxf(a, 0.f) + beta1[d];
            }
            *(float4*)(Hs + (size_t)n * SROW + d0 + 4 * q) =
                make_float4(hq[0], hq[1], hq[2], hq[3]);
        }
    }
    __syncthreads();

    float ti[16], tj[16];

    // ================= conv1 =================
    conv_full(Hs, n, d0, We1, ti, tj);
    __syncthreads();                       // Hs reads done -> scratch reuse ok

    // tj -> transpose scratch
#pragma unroll
    for (int j = 0; j < 16; ++j) Ts[l * TPAD + j] = tj[j];
    __syncthreads();

    // column reduce: 16 in-lane + 4 shuffles
    {
        float mx = -FMAXV, mn = FMAXV;
#pragma unroll
        for (int r = 0; r < 16; ++r) {
            float v = Ts[(cq * 16 + r) * TPAD + jd];
            mx = fmaxf(mx, v); mn = fminf(mn, v);
        }
        mx = fmaxf(mx, __shfl_xor(mx, 1, 64));
        mx = fmaxf(mx, __shfl_xor(mx, 2, 64));
        mn = fminf(mn, __shfl_xor(mn, 1, 64));
        mn = fminf(mn, __shfl_xor(mn, 2, 64));
        if (cq == 0) { PTmax[ng][d0 + jd] = mx; PTmin[ng][d0 + jd] = mn; }
    }
    __syncthreads();

    // combine 4 node-groups
    {
        const int t = threadIdx.x;
        if (t < DD)
            RM[t] = fmaxf(fmaxf(PTmax[0][t], PTmax[1][t]),
                          fmaxf(PTmax[2][t], PTmax[3][t]));
        else if (t < 2 * DD) {
            const int d = t - DD;
            RMn[d] = fminf(fminf(PTmin[0][d], PTmin[1][d]),
                           fminf(PTmin[2][d], PTmin[3][d]));
        }
    }
    __syncthreads();

    // conv1 epilogue -> Hs rows (monotone bn o max)
    {
#pragma unroll
        for (int q = 0; q < 4; ++q) {
            float4 rmx = *(const float4*)(&RM[d0 + 4 * q]);    // broadcast
            float4 rmn = *(const float4*)(&RMn[d0 + 4 * q]);   // broadcast
            const float rmax[4] = {rmx.x, rmx.y, rmx.z, rmx.w};
            const float rmin[4] = {rmn.x, rmn.y, rmn.z, rmn.w};
            float hq[4];
#pragma unroll
            for (int u = 0; u < 4; ++u) {
                const int d = d0 + 4 * q + u;
                const float gv = ge1[d];
                const float sv = ti[4*q+u] + (gv >= 0.f ? rmax[u] : rmin[u]) + be1[d];
                hq[u] = gv * fmaxf(sv, 0.f) + bte1[d];
            }
            *(float4*)(Hs + (size_t)n * SROW + d0 + 4 * q) =
                make_float4(hq[0], hq[1], hq[2], hq[3]);
        }
    }
    __syncthreads();

    // ================= conv2 =================
    conv_full(Hs, n, d0, We2, ti, tj);
    __syncthreads();

#pragma unroll
    for (int j = 0; j < 16; ++j) Ts[l * TPAD + j] = tj[j];
    __syncthreads();

    {
        float mx = -FMAXV, mn = FMAXV;
#pragma unroll
        for (int r = 0; r < 16; ++r) {
            float v = Ts[(cq * 16 + r) * TPAD + jd];
            mx = fmaxf(mx, v); mn = fminf(mn, v);
        }
        mx = fmaxf(mx, __shfl_xor(mx, 1, 64));
        mx = fmaxf(mx, __shfl_xor(mx, 2, 64));
        mn = fminf(mn, __shfl_xor(mn, 1, 64));
        mn = fminf(mn, __shfl_xor(mn, 2, 64));
        if (cq == 0) { PTmax[ng][d0 + jd] = mx; PTmin[ng][d0 + jd] = mn; }
    }
    __syncthreads();

    {
        const int t = threadIdx.x;
        if (t < DD)
            RM[t] = fmaxf(fmaxf(PTmax[0][t], PTmax[1][t]),
                          fmaxf(PTmax[2][t], PTmax[3][t]));
        else if (t < 2 * DD) {
            const int d = t - DD;
            RMn[d] = fminf(fminf(PTmin[0][d], PTmin[1][d]),
                           fminf(PTmin[2][d], PTmin[3][d]));
        }
    }
    __syncthreads();

    // conv2 epilogue -> h3, into transpose scratch for pooling
    {
#pragma unroll
        for (int q = 0; q < 4; ++q) {
            float4 rmx = *(const float4*)(&RM[d0 + 4 * q]);
            float4 rmn = *(const float4*)(&RMn[d0 + 4 * q]);
            const float rmax[4] = {rmx.x, rmx.y, rmx.z, rmx.w};
            const float rmin[4] = {rmn.x, rmn.y, rmn.z, rmn.w};
#pragma unroll
            for (int u = 0; u < 4; ++u) {
                const int d = d0 + 4 * q + u;
                const float gv = ge2[d];
                const float sv = ti[4*q+u] + (gv >= 0.f ? rmax[u] : rmin[u]) + be2[d];
                Ts[l * TPAD + 4 * q + u] = gv * fmaxf(sv, 0.f) + bte2[d];
            }
        }
    }
    __syncthreads();

    // pooling: column reduce sum & max
    {
        float s = 0.f, mx = -FMAXV;
#pragma unroll
        for (int r = 0; r < 16; ++r) {
            float v = Ts[(cq * 16 + r) * TPAD + jd];
            s += v; mx = fmaxf(mx, v);
        }
        s += __shfl_xor(s, 1, 64);
        s += __shfl_xor(s, 2, 64);
        mx = fmaxf(mx, __shfl_xor(mx, 1, 64));
        mx = fmaxf(mx, __shfl_xor(mx, 2, 64));
        if (cq == 0) { PS[ng][d0 + jd] = s; PM[ng][d0 + jd] = mx; }
    }
    __syncthreads();

    // pooling finalize + head MLP
    const int t = threadIdx.x;
    if (t < DD) {
        xg[t] = (PS[0][t] + PS[1][t] + PS[2][t] + PS[3][t]) * (1.f / 256.f);
    } else if (t < 2 * DD) {
        const int d = t - DD;
        xg[t] = fmaxf(fmaxf(PM[0][d], PM[1][d]), fmaxf(PM[2][d], PM[3][d]));
    }
    __syncthreads();
    if (t < DD) {
        float a = bg1[t];
#pragma unroll
        for (int k = 0; k < 2 * DD; ++k) a = fmaf(xg[k], Wg1[k * DD + t], a);
        hid[t] = fmaxf(a, 0.f);
    }
    __syncthreads();
    if (t < 2) {
        float o = bg2[t];
#pragma unroll
        for (int j = 0; j < DD; ++j) o = fmaf(hid[j], Wg2[j * 2 + t], o);
        out[b * 2 + t] = o;
    }
}

extern "C" void kernel_launch(void* const* d_in, const int* in_sizes, int n_in,
                              void* d_out, int out_size, void* d_ws, size_t ws_size,
                              hipStream_t stream) {
    const float* x     = (const float*)d_in[0];
    const float* W1    = (const float*)d_in[1];
    const float* b1    = (const float*)d_in[2];
    const float* g1    = (const float*)d_in[3];
    const float* beta1 = (const float*)d_in[4];
    const float* We1   = (const float*)d_in[5];
    const float* be1   = (const float*)d_in[6];
    const float* ge1   = (const float*)d_in[7];
    const float* bte1  = (const float*)d_in[8];
    const float* We2   = (const float*)d_in[9];
    const float* be2   = (const float*)d_in[10];
    const float* ge2   = (const float*)d_in[11];
    const float* bte2  = (const float*)d_in[12];
    const float* Wg1   = (const float*)d_in[13];
    const float* bg1   = (const float*)d_in[14];
    const float* Wg2   = (const float*)d_in[15];
    const float* bg2   = (const float*)d_in[16];

    k_all<<<dim3(NB), dim3(1024), 0, stream>>>(
        x, W1, b1, g1, beta1,
        We1, be1, ge1, bte1,
        We2, be2, ge2, bte2,
        Wg1, bg1, Wg2, bg2, (float*)d_out);
}